// Round 16
// baseline (2261.588 us; speedup 1.0000x reference)
//
#include <hip/hip_runtime.h>
#include <stdint.h>
#include <stddef.h>

typedef short v8s __attribute__((ext_vector_type(8)));
typedef float v4f __attribute__((ext_vector_type(4)));
typedef unsigned short v4u16 __attribute__((ext_vector_type(4)));

__device__ __forceinline__ unsigned short f2bf(float f) {
  union { float f; uint32_t u; } v; v.f = f;
  uint32_t r = (v.u + 0x7FFFu + ((v.u >> 16) & 1u)) >> 16;
  return (unsigned short)r;
}

__device__ __forceinline__ void gl_lds16(const void* g, void* l) {
  __builtin_amdgcn_global_load_lds(
      (__attribute__((address_space(1))) void*)(uintptr_t)(g),
      (__attribute__((address_space(3))) void*)(uintptr_t)(l), 16, 0, 0);
}

// ---------- prep: Us[o,k] = bf16(U[o,k] * relu(S[k]+delta[k])) ----------
__global__ __launch_bounds__(256) void k_prep_us(const float* __restrict__ U,
                                                 const float* __restrict__ S,
                                                 const float* __restrict__ delta,
                                                 unsigned short* __restrict__ Us) {
  int idx = blockIdx.x * 256 + threadIdx.x;
  int e0 = idx * 8;
  int col = e0 & 4095;
  float4 u0 = *(const float4*)(U + e0);
  float4 u1 = *(const float4*)(U + e0 + 4);
  float4 s0 = *(const float4*)(S + col);
  float4 s1 = *(const float4*)(S + col + 4);
  float4 d0 = *(const float4*)(delta + col);
  float4 d1 = *(const float4*)(delta + col + 4);
  float uu[8] = {u0.x, u0.y, u0.z, u0.w, u1.x, u1.y, u1.z, u1.w};
  float se[8] = {s0.x + d0.x, s0.y + d0.y, s0.z + d0.z, s0.w + d0.w,
                 s1.x + d1.x, s1.y + d1.y, s1.z + d1.z, s1.w + d1.w};
  v8s o;
#pragma unroll
  for (int j = 0; j < 8; ++j) {
    float sv = se[j] > 0.f ? se[j] : 0.f;
    o[j] = (short)f2bf(uu[j] * sv);
  }
  *(v8s*)(Us + e0) = o;
}

// ---------- prep: xb = bf16(x) ----------
__global__ __launch_bounds__(256) void k_prep_x(const float* __restrict__ in,
                                                unsigned short* __restrict__ out) {
  int idx = blockIdx.x * 256 + threadIdx.x;
  int e0 = idx * 8;
  float4 a = *(const float4*)(in + e0);
  float4 b = *(const float4*)(in + e0 + 4);
  float f[8] = {a.x, a.y, a.z, a.w, b.x, b.y, b.z, b.w};
  v8s o;
#pragma unroll
  for (int j = 0; j < 8; ++j) o[j] = (short)f2bf(f[j]);
  *(v8s*)(out + e0) = o;
}

// ---------- kron: Vo[k,i] = sum_j V[k,j] * (Q1xQ2xQ3)[i,j] ----------
__device__ __forceinline__ int PADI(int e) { return e + 4 * (e >> 6); }

__global__ __launch_bounds__(256) void k_kron(const float* __restrict__ V,
                                              const float* __restrict__ Q1,
                                              const float* __restrict__ Q2,
                                              const float* __restrict__ Q3,
                                              unsigned short* __restrict__ Vo) {
  __shared__ float bufA[4352];
  __shared__ float bufB[4352];
  __shared__ float q1s[256], q2s[256], q3s[256];
  int t = threadIdx.x;
  int row = blockIdx.x;
  q1s[t] = Q1[t]; q2s[t] = Q2[t]; q3s[t] = Q3[t];
  const float* vrow = V + (size_t)row * 4096;
#pragma unroll
  for (int i = 0; i < 4; ++i) {
    int idx = t + i * 256;
    float4 v = ((const float4*)vrow)[idx];
    int e = idx * 4;
    *(float4*)&bufA[PADI(e)] = v;
  }
  __syncthreads();
  {
    float r[16];
    int base = PADI(t * 16);
#pragma unroll
    for (int j3 = 0; j3 < 16; ++j3) r[j3] = bufA[base + j3];
#pragma unroll
    for (int i3 = 0; i3 < 16; ++i3) {
      float s = 0.f;
#pragma unroll
      for (int j3 = 0; j3 < 16; ++j3) s += r[j3] * q3s[i3 * 16 + j3];
      bufB[base + i3] = s;
    }
  }
  __syncthreads();
  {
    int j1 = t >> 4, i3 = t & 15;
    float r[16];
#pragma unroll
    for (int j2 = 0; j2 < 16; ++j2) r[j2] = bufB[PADI(j1 * 256 + j2 * 16 + i3)];
#pragma unroll
    for (int i2 = 0; i2 < 16; ++i2) {
      float s = 0.f;
#pragma unroll
      for (int j2 = 0; j2 < 16; ++j2) s += r[j2] * q2s[i2 * 16 + j2];
      bufA[PADI(j1 * 256 + i2 * 16 + i3)] = s;
    }
  }
  __syncthreads();
  {
    int i2 = t >> 4, i3 = t & 15;
    float r[16];
#pragma unroll
    for (int j1 = 0; j1 < 16; ++j1) r[j1] = bufA[PADI(j1 * 256 + i2 * 16 + i3)];
    unsigned short* orow = Vo + (size_t)row * 4096;
#pragma unroll
    for (int i1 = 0; i1 < 16; ++i1) {
      float s = 0.f;
#pragma unroll
      for (int j1 = 0; j1 < 16; ++j1) s += r[j1] * q1s[i1 * 16 + j1];
      orow[i1 * 256 + i2 * 16 + i3] = f2bf(s);
    }
  }
}

// ---------- transpose 4096x4096 bf16 ----------
__global__ __launch_bounds__(256) void k_transpose(const unsigned short* __restrict__ in,
                                                   unsigned short* __restrict__ out) {
  __shared__ unsigned short tile[64][68];
  int bx = blockIdx.x & 63;
  int by = blockIdx.x >> 6;
  int t = threadIdx.x;
#pragma unroll
  for (int q = 0; q < 4; ++q) {
    int i = t + q * 256;
    int r = i >> 4;
    int c = (i & 15) * 4;
    v4u16 v = *(const v4u16*)(in + (size_t)(by * 64 + r) * 4096 + bx * 64 + c);
    tile[r][c] = v[0]; tile[r][c + 1] = v[1]; tile[r][c + 2] = v[2]; tile[r][c + 3] = v[3];
  }
  __syncthreads();
#pragma unroll
  for (int q = 0; q < 4; ++q) {
    int i = t + q * 256;
    int r = i >> 4;
    int c = (i & 15) * 4;
    v4u16 v;
    v[0] = tile[c][r]; v[1] = tile[c + 1][r]; v[2] = tile[c + 2][r]; v[3] = tile[c + 3][r];
    *(v4u16*)(out + (size_t)(bx * 64 + r) * 4096 + by * 64 + c) = v;
  }
}

// ========== GEMM1: 256x256, m201-faithful (R14 best, unchanged) ==========
#define STGH(MATP, MI, H, D, T) do {                                       \
    gl_lds16((MATP) + (size_t)((H) * 128) * K + (T) * 64,                  \
             &lds[(D) * 32768 + (MI) * 16384 + (H) * 8192 + tid * 8]);     \
    gl_lds16((MATP) + (size_t)((H) * 128 + 64) * K + (T) * 64,             \
             &lds[(D) * 32768 + (MI) * 16384 + (H) * 8192 + 4096 + tid * 8]); \
  } while (0)

#define RA(D, I, S) \
  (*(const v8s*)&lds[(D) * 32768 + abase + (I) * 1024 + ((S) ? kc1 : kc0)])
#define RB(D, J, S) \
  (*(const v8s*)&lds[(D) * 32768 + 16384 + bbase + (J) * 1024 + ((S) ? kc1 : kc0)])

#define MM(I, NN, AV, BV) \
  acc[(I)][(NN)] = __builtin_amdgcn_mfma_f32_16x16x32_bf16(AV, BV, acc[(I)][(NN)], 0, 0, 0)

#define MMQ(IQ, JQ, BX) do {                                               \
    MM((IQ)+0, (JQ)+0, aF[0][0], BX[0][0]); MM((IQ)+1, (JQ)+0, aF[1][0], BX[0][0]); \
    MM((IQ)+2, (JQ)+0, aF[2][0], BX[0][0]); MM((IQ)+3, (JQ)+0, aF[3][0], BX[0][0]); \
    MM((IQ)+0, (JQ)+1, aF[0][0], BX[1][0]); MM((IQ)+1, (JQ)+1, aF[1][0], BX[1][0]); \
    MM((IQ)+2, (JQ)+1, aF[2][0], BX[1][0]); MM((IQ)+3, (JQ)+1, aF[3][0], BX[1][0]); \
    MM((IQ)+0, (JQ)+0, aF[0][1], BX[0][1]); MM((IQ)+1, (JQ)+0, aF[1][1], BX[0][1]); \
    MM((IQ)+2, (JQ)+0, aF[2][1], BX[0][1]); MM((IQ)+3, (JQ)+0, aF[3][1], BX[0][1]); \
    MM((IQ)+0, (JQ)+1, aF[0][1], BX[1][1]); MM((IQ)+1, (JQ)+1, aF[1][1], BX[1][1]); \
    MM((IQ)+2, (JQ)+1, aF[2][1], BX[1][1]); MM((IQ)+3, (JQ)+1, aF[3][1], BX[1][1]); \
  } while (0)

#define PH(RD, STGX, HINT8, IQ, JQ, BX, DOVM) do {                         \
    RD;                                                                    \
    STGX;                                                                  \
    if (HINT8) asm volatile("s_waitcnt lgkmcnt(8)" ::: "memory");          \
    __builtin_amdgcn_sched_barrier(0);                                     \
    __builtin_amdgcn_s_barrier();                                          \
    asm volatile("s_waitcnt lgkmcnt(0)" ::: "memory");                     \
    __builtin_amdgcn_sched_barrier(0);                                     \
    __builtin_amdgcn_s_setprio(1);                                         \
    MMQ(IQ, JQ, BX);                                                       \
    __builtin_amdgcn_s_setprio(0);                                         \
    if (DOVM) asm volatile("s_waitcnt vmcnt(4)" ::: "memory");             \
    __builtin_amdgcn_s_barrier();                                          \
    __builtin_amdgcn_sched_barrier(0);                                     \
  } while (0)

#define RD_Q0(D) do {                                                      \
    aF[0][0]=RA(D,0,0); aF[0][1]=RA(D,0,1); aF[1][0]=RA(D,1,0); aF[1][1]=RA(D,1,1); \
    aF[2][0]=RA(D,2,0); aF[2][1]=RA(D,2,1); aF[3][0]=RA(D,3,0); aF[3][1]=RA(D,3,1); \
    bF0[0][0]=RB(D,0,0); bF0[0][1]=RB(D,0,1); bF0[1][0]=RB(D,1,0); bF0[1][1]=RB(D,1,1); \
  } while (0)
#define RD_Q1(D) do {                                                      \
    bF1[0][0]=RB(D,2,0); bF1[0][1]=RB(D,2,1); bF1[1][0]=RB(D,3,0); bF1[1][1]=RB(D,3,1); \
  } while (0)
#define RD_Q2(D) do {                                                      \
    aF[0][0]=RA(D,4,0); aF[0][1]=RA(D,4,1); aF[1][0]=RA(D,5,0); aF[1][1]=RA(D,5,1); \
    aF[2][0]=RA(D,6,0); aF[2][1]=RA(D,6,1); aF[3][0]=RA(D,7,0); aF[3][1]=RA(D,7,1); \
  } while (0)

__global__ __launch_bounds__(512, 2) void k_gemm256(const unsigned short* __restrict__ A,
                                                    const unsigned short* __restrict__ B,
                                                    unsigned short* __restrict__ Cp,
                                                    int K, int N, int nbn) {
  __shared__ unsigned short lds[65536];  // 128 KiB
  const int NT = K >> 6;
  const int NM = NT - 1;
  int nwg = gridDim.x;
  int bid = blockIdx.x;
  int wg = (bid & 7) * (nwg >> 3) + (bid >> 3);
  int bm = wg / nbn, bn = wg % nbn;
  int tid = threadIdx.x;
  int lane = tid & 63;
  int l4 = lane & 15;
  int wid = tid >> 6;
  int wr = wid >> 2, wc = wid & 3;

  int srow = tid >> 3;
  int scol = ((tid & 7) ^ (srow & 7)) * 8;
  const unsigned short* Ap = A + (size_t)(bm * 256 + srow) * K + scol;
  const unsigned short* Bp = B + (size_t)(bn * 256 + srow) * K + scol;

  int kc0 = (((lane >> 4)) ^ (l4 & 7)) * 8;
  int kc1 = (((lane >> 4) + 4) ^ (l4 & 7)) * 8;
  int abase = wr * 8192 + l4 * 64;
  int bbase = (wc >> 1) * 8192 + ((wc & 1) * 64 + l4) * 64;

  v4f acc[8][4];
#pragma unroll
  for (int i = 0; i < 8; ++i)
#pragma unroll
    for (int j = 0; j < 4; ++j) acc[i][j] = (v4f){0.f, 0.f, 0.f, 0.f};
  v8s aF[4][2];
  v8s bF0[2][2];
  v8s bF1[2][2];

  STGH(Ap, 0, 0, 0, 0); STGH(Ap, 0, 1, 0, 0);
  STGH(Bp, 1, 0, 0, 0); STGH(Bp, 1, 1, 0, 0);
  STGH(Bp, 1, 0, 1, 1); STGH(Bp, 1, 1, 1, 1);
  asm volatile("s_waitcnt vmcnt(4)" ::: "memory");
  __builtin_amdgcn_s_barrier();
  __builtin_amdgcn_sched_barrier(0);

  for (int it = 0; it < NT / 2; ++it) {
    int sA0 = (2 * it + 1) & NM;
    int sB0 = (2 * it + 2) & NM;
    int sB1 = (2 * it + 3) & NM;
    PH(RD_Q0(0), STGH(Ap, 0, 0, 1, sA0), 1, 0, 0, bF0, 0);
    PH(RD_Q1(0), STGH(Ap, 0, 1, 1, sA0), 0, 0, 2, bF1, 0);
    PH(RD_Q2(0), STGH(Bp, 1, 0, 0, sB0), 0, 4, 0, bF0, 0);
    PH(,         STGH(Bp, 1, 1, 0, sB0), 0, 4, 2, bF1, 1);
    PH(RD_Q0(1), STGH(Ap, 0, 0, 0, sB0), 1, 0, 0, bF0, 0);
    PH(RD_Q1(1), STGH(Ap, 0, 1, 0, sB0), 0, 0, 2, bF1, 0);
    PH(RD_Q2(1), STGH(Bp, 1, 0, 1, sB1), 0, 4, 0, bF0, 0);
    PH(,         STGH(Bp, 1, 1, 1, sB1), 0, 4, 2, bF1, 1);
  }
  asm volatile("s_waitcnt vmcnt(0)" ::: "memory");

  int row0 = bm * 256 + wr * 128 + ((lane >> 4) << 2);
  int col0 = bn * 256 + wc * 64 + l4;
#pragma unroll
  for (int m = 0; m < 8; ++m)
#pragma unroll
    for (int n = 0; n < 4; ++n)
#pragma unroll
      for (int r = 0; r < 4; ++r)
        Cp[(size_t)(row0 + m * 16 + r) * N + col0 + n * 16] = f2bf(acc[m][n][r]);
}

// ========== GEMM2: 256x512 fat block, 8 waves of 128x128, BK=32 ==========
// Same FLOP/tile as 256^2 K64 but 128 ds_read_b128 instead of 192 (-33% LDS
// work). LDS 96 KiB dbuf: buf b at b*24576 shorts {A[256][32] @0, B[512][32]
// @8192}; R2's proven 0-conflict swizzle (byte f = c ^ (((row>>1)&3)<<4)).
// 4 phases/tile: q0 reads A0-3+B0-3 (stage A), q1 B4-7 (stage B01),
// q2 A4-7 (stage B23), q3 none (vmcnt(0)). acc[8][8]=256 VGPR, cap 512 (512,1).

#define RAW_(D, M) (*(const v8s*)&lds[(D) * 24576 + wabase + (M) * 512])
#define RBW_(D, NN) (*(const v8s*)&lds[(D) * 24576 + wbbase + (NN) * 512])

#define MMW(I, NN, AV, BV) \
  acc[(I)][(NN)] = __builtin_amdgcn_mfma_f32_16x16x32_bf16(AV, BV, acc[(I)][(NN)], 0, 0, 0)

#define MMQW(MB, NB, AR, BR) do {                                          \
    MMW((MB)+0, (NB)+0, AR[0], BR[0]); MMW((MB)+1, (NB)+0, AR[1], BR[0]);  \
    MMW((MB)+2, (NB)+0, AR[2], BR[0]); MMW((MB)+3, (NB)+0, AR[3], BR[0]);  \
    MMW((MB)+0, (NB)+1, AR[0], BR[1]); MMW((MB)+1, (NB)+1, AR[1], BR[1]);  \
    MMW((MB)+2, (NB)+1, AR[2], BR[1]); MMW((MB)+3, (NB)+1, AR[3], BR[1]);  \
    MMW((MB)+0, (NB)+2, AR[0], BR[2]); MMW((MB)+1, (NB)+2, AR[1], BR[2]);  \
    MMW((MB)+2, (NB)+2, AR[2], BR[2]); MMW((MB)+3, (NB)+2, AR[3], BR[2]);  \
    MMW((MB)+0, (NB)+3, AR[0], BR[3]); MMW((MB)+1, (NB)+3, AR[1], BR[3]);  \
    MMW((MB)+2, (NB)+3, AR[2], BR[3]); MMW((MB)+3, (NB)+3, AR[3], BR[3]);  \
  } while (0)

#define PHW(RD, STGX, MB, NB, AR, BR, DOVM) do {                           \
    RD;                                                                    \
    STGX;                                                                  \
    __builtin_amdgcn_sched_barrier(0);                                     \
    __builtin_amdgcn_s_barrier();                                          \
    asm volatile("s_waitcnt lgkmcnt(0)" ::: "memory");                     \
    __builtin_amdgcn_sched_barrier(0);                                     \
    __builtin_amdgcn_s_setprio(1);                                         \
    MMQW(MB, NB, AR, BR);                                                  \
    __builtin_amdgcn_s_setprio(0);                                         \
    if (DOVM) asm volatile("s_waitcnt vmcnt(0)" ::: "memory");             \
    __builtin_amdgcn_s_barrier();                                          \
    __builtin_amdgcn_sched_barrier(0);                                     \
  } while (0)

#define TILE_W(D, KOFF) do {                                               \
    PHW({ aR[0]=RAW_(D,0); aR[1]=RAW_(D,1); aR[2]=RAW_(D,2); aR[3]=RAW_(D,3); \
          bR[0]=RBW_(D,0); bR[1]=RBW_(D,1); bR[2]=RBW_(D,2); bR[3]=RBW_(D,3); }, \
        { gl_lds16(As0 + (KOFF), &lds[(D ^ 1) * 24576 + tid * 8]);         \
          gl_lds16(As1 + (KOFF), &lds[(D ^ 1) * 24576 + 4096 + tid * 8]); }, \
        0, 0, aR, bR, 0);                                                  \
    PHW({ bG[0]=RBW_(D,4); bG[1]=RBW_(D,5); bG[2]=RBW_(D,6); bG[3]=RBW_(D,7); }, \
        { gl_lds16(Bs0 + (KOFF), &lds[(D ^ 1) * 24576 + 8192 + tid * 8]);  \
          gl_lds16(Bs1 + (KOFF), &lds[(D ^ 1) * 24576 + 12288 + tid * 8]); }, \
        0, 4, aR, bG, 0);                                                  \
    PHW({ aR[0]=RAW_(D,4); aR[1]=RAW_(D,5); aR[2]=RAW_(D,6); aR[3]=RAW_(D,7); }, \
        { gl_lds16(Bs2 + (KOFF), &lds[(D ^ 1) * 24576 + 16384 + tid * 8]); \
          gl_lds16(Bs3 + (KOFF), &lds[(D ^ 1) * 24576 + 20480 + tid * 8]); }, \
        4, 0, aR, bR, 0);                                                  \
    PHW(, , 4, 4, aR, bG, 1);                                              \
  } while (0)

__global__ __launch_bounds__(512, 1) void k_gemmw(const unsigned short* __restrict__ A,
                                                  const unsigned short* __restrict__ B,
                                                  float* __restrict__ Cp,
                                                  int K, int N, int nbn) {
  __shared__ unsigned short lds[49152];  // 96 KiB
  const int NT = K >> 5;                 // 128
  const int NM = NT - 1;
  int nwg = gridDim.x;
  int bid = blockIdx.x;
  int wg = (bid & 7) * (nwg >> 3) + (bid >> 3);  // bijective XCD swizzle (nwg%8==0)
  int bm = wg / nbn, bn = wg % nbn;
  int tid = threadIdx.x;
  int lane = tid & 63;
  int wid = tid >> 6;
  int wr = wid >> 2, wc = wid & 3;              // 2M x 4N waves of 128x128

  const unsigned short* Ab = A + (size_t)bm * 256 * K;
  const unsigned short* Bb = B + (size_t)bn * 512 * K;

  // staging source (pre-swizzled, R2-proven): row srow, swizzled 16B slot
  int srow = tid >> 2;                              // 0..127
  int scol = 8 * ((tid & 3) ^ ((tid >> 3) & 3));
  const unsigned short* As0 = Ab + (size_t)srow * K + scol;
  const unsigned short* As1 = As0 + (size_t)128 * K;
  const unsigned short* Bs0 = Bb + (size_t)srow * K + scol;
  const unsigned short* Bs1 = Bs0 + (size_t)128 * K;
  const unsigned short* Bs2 = Bs0 + (size_t)256 * K;
  const unsigned short* Bs3 = Bs0 + (size_t)384 * K;

  // frag-read lane constant (shorts): row (lane&15), 16B slot (lane>>4) ^ swz
  int acb = (lane & 15) * 32 + (((lane >> 4) ^ (((lane & 15) >> 1) & 3)) * 8);
  int wabase = wr * 4096 + acb;          // A rows wr*128..
  int wbbase = 8192 + wc * 4096 + acb;   // B rows wc*128..

  v4f acc[8][8];
#pragma unroll
  for (int i = 0; i < 8; ++i)
#pragma unroll
    for (int j = 0; j < 8; ++j) acc[i][j] = (v4f){0.f, 0.f, 0.f, 0.f};
  v8s aR[4], bR[4], bG[4];

  // prologue: tile 0 -> buf 0 (6 ops), full drain
  gl_lds16(As0, &lds[tid * 8]);
  gl_lds16(As1, &lds[4096 + tid * 8]);
  gl_lds16(Bs0, &lds[8192 + tid * 8]);
  gl_lds16(Bs1, &lds[12288 + tid * 8]);
  gl_lds16(Bs2, &lds[16384 + tid * 8]);
  gl_lds16(Bs3, &lds[20480 + tid * 8]);
  asm volatile("s_waitcnt vmcnt(0)" ::: "memory");
  __builtin_amdgcn_s_barrier();
  __builtin_amdgcn_sched_barrier(0);

  for (int it = 0; it < NT / 2; ++it) {
    int k0 = ((2 * it + 1) & NM) * 32;
    int k1 = ((2 * it + 2) & NM) * 32;
    TILE_W(0, k0);
    TILE_W(1, k1);
  }
  asm volatile("s_waitcnt vmcnt(0)" ::: "memory");

  int row0 = bm * 256 + wr * 128 + ((lane >> 4) << 2);
  int col0 = bn * 512 + wc * 128 + (lane & 15);
#pragma unroll
  for (int m = 0; m < 8; ++m)
#pragma unroll
    for (int n = 0; n < 8; ++n)
#pragma unroll
      for (int r = 0; r < 4; ++r)
        Cp[(size_t)(row0 + m * 16 + r) * N + col0 + n * 16] = acc[m][n][r];
}

extern "C" void kernel_launch(void* const* d_in, const int* in_sizes, int n_in,
                              void* d_out, int out_size, void* d_ws, size_t ws_size,
                              hipStream_t stream) {
  const float* x = (const float*)d_in[0];
  const float* U = (const float*)d_in[1];
  const float* S = (const float*)d_in[2];
  const float* V = (const float*)d_in[3];
  const float* delta = (const float*)d_in[4];
  const float* Q1 = (const float*)d_in[5];
  const float* Q2 = (const float*)d_in[6];
  const float* Q3 = (const float*)d_in[7];

  char* ws = (char*)d_ws;
  unsigned short* Us = (unsigned short*)(ws);
  unsigned short* Mt = (unsigned short*)(ws + 33554432);
  unsigned short* xb = (unsigned short*)(ws + 67108864);
  char* oc = (char*)d_out;
  unsigned short* Vo = (unsigned short*)(oc);
  unsigned short* VoT = (unsigned short*)(oc + 33554432);
  float* out = (float*)d_out;

  k_prep_us<<<8192, 256, 0, stream>>>(U, S, delta, Us);
  k_kron<<<4096, 256, 0, stream>>>(V, Q1, Q2, Q3, Vo);
  k_transpose<<<4096, 256, 0, stream>>>(Vo, VoT);
  k_prep_x<<<16384, 256, 0, stream>>>(x, xb);
  // Mt[o,i] = sum_k Us[o,k] * VoT[i,k]   (4096x4096x4096) - R14 kernel
  k_gemm256<<<256, 512, 0, stream>>>(Us, VoT, Mt, 4096, 4096, 16);
  // out[n,o] = sum_i xb[n,i] * Mt[o,i]   (8192x4096x4096) - fat 256x512 tile
  k_gemmw<<<256, 512, 0, stream>>>(xb, Mt, out, 4096, 4096, 8);
}

// Round 17
// 447.349 us; speedup vs baseline: 5.0555x; 5.0555x over previous
//
#include <hip/hip_runtime.h>
#include <stdint.h>
#include <stddef.h>

typedef short v8s __attribute__((ext_vector_type(8)));
typedef float v4f __attribute__((ext_vector_type(4)));
typedef unsigned short v4u16 __attribute__((ext_vector_type(4)));

__device__ __forceinline__ unsigned short f2bf(float f) {
  union { float f; uint32_t u; } v; v.f = f;
  uint32_t r = (v.u + 0x7FFFu + ((v.u >> 16) & 1u)) >> 16;
  return (unsigned short)r;
}

__device__ __forceinline__ void gl_lds16(const void* g, void* l) {
  __builtin_amdgcn_global_load_lds(
      (__attribute__((address_space(1))) void*)(uintptr_t)(g),
      (__attribute__((address_space(3))) void*)(uintptr_t)(l), 16, 0, 0);
}

// ---------- prep: Us[o,k] = bf16(U[o,k] * relu(S[k]+delta[k])) ----------
__global__ __launch_bounds__(256) void k_prep_us(const float* __restrict__ U,
                                                 const float* __restrict__ S,
                                                 const float* __restrict__ delta,
                                                 unsigned short* __restrict__ Us) {
  int idx = blockIdx.x * 256 + threadIdx.x;
  int e0 = idx * 8;
  int col = e0 & 4095;
  float4 u0 = *(const float4*)(U + e0);
  float4 u1 = *(const float4*)(U + e0 + 4);
  float4 s0 = *(const float4*)(S + col);
  float4 s1 = *(const float4*)(S + col + 4);
  float4 d0 = *(const float4*)(delta + col);
  float4 d1 = *(const float4*)(delta + col + 4);
  float uu[8] = {u0.x, u0.y, u0.z, u0.w, u1.x, u1.y, u1.z, u1.w};
  float se[8] = {s0.x + d0.x, s0.y + d0.y, s0.z + d0.z, s0.w + d0.w,
                 s1.x + d1.x, s1.y + d1.y, s1.z + d1.z, s1.w + d1.w};
  v8s o;
#pragma unroll
  for (int j = 0; j < 8; ++j) {
    float sv = se[j] > 0.f ? se[j] : 0.f;
    o[j] = (short)f2bf(uu[j] * sv);
  }
  *(v8s*)(Us + e0) = o;
}

// ---------- prep: xb = bf16(x) ----------
__global__ __launch_bounds__(256) void k_prep_x(const float* __restrict__ in,
                                                unsigned short* __restrict__ out) {
  int idx = blockIdx.x * 256 + threadIdx.x;
  int e0 = idx * 8;
  float4 a = *(const float4*)(in + e0);
  float4 b = *(const float4*)(in + e0 + 4);
  float f[8] = {a.x, a.y, a.z, a.w, b.x, b.y, b.z, b.w};
  v8s o;
#pragma unroll
  for (int j = 0; j < 8; ++j) o[j] = (short)f2bf(f[j]);
  *(v8s*)(out + e0) = o;
}

// ---------- kron: Vo[k,i] = sum_j V[k,j] * (Q1xQ2xQ3)[i,j] ----------
__device__ __forceinline__ int PADI(int e) { return e + 4 * (e >> 6); }

__global__ __launch_bounds__(256) void k_kron(const float* __restrict__ V,
                                              const float* __restrict__ Q1,
                                              const float* __restrict__ Q2,
                                              const float* __restrict__ Q3,
                                              unsigned short* __restrict__ Vo) {
  __shared__ float bufA[4352];
  __shared__ float bufB[4352];
  __shared__ float q1s[256], q2s[256], q3s[256];
  int t = threadIdx.x;
  int row = blockIdx.x;
  q1s[t] = Q1[t]; q2s[t] = Q2[t]; q3s[t] = Q3[t];
  const float* vrow = V + (size_t)row * 4096;
#pragma unroll
  for (int i = 0; i < 4; ++i) {
    int idx = t + i * 256;
    float4 v = ((const float4*)vrow)[idx];
    int e = idx * 4;
    *(float4*)&bufA[PADI(e)] = v;
  }
  __syncthreads();
  {
    float r[16];
    int base = PADI(t * 16);
#pragma unroll
    for (int j3 = 0; j3 < 16; ++j3) r[j3] = bufA[base + j3];
#pragma unroll
    for (int i3 = 0; i3 < 16; ++i3) {
      float s = 0.f;
#pragma unroll
      for (int j3 = 0; j3 < 16; ++j3) s += r[j3] * q3s[i3 * 16 + j3];
      bufB[base + i3] = s;
    }
  }
  __syncthreads();
  {
    int j1 = t >> 4, i3 = t & 15;
    float r[16];
#pragma unroll
    for (int j2 = 0; j2 < 16; ++j2) r[j2] = bufB[PADI(j1 * 256 + j2 * 16 + i3)];
#pragma unroll
    for (int i2 = 0; i2 < 16; ++i2) {
      float s = 0.f;
#pragma unroll
      for (int j2 = 0; j2 < 16; ++j2) s += r[j2] * q2s[i2 * 16 + j2];
      bufA[PADI(j1 * 256 + i2 * 16 + i3)] = s;
    }
  }
  __syncthreads();
  {
    int i2 = t >> 4, i3 = t & 15;
    float r[16];
#pragma unroll
    for (int j1 = 0; j1 < 16; ++j1) r[j1] = bufA[PADI(j1 * 256 + i2 * 16 + i3)];
    unsigned short* orow = Vo + (size_t)row * 4096;
#pragma unroll
    for (int i1 = 0; i1 < 16; ++i1) {
      float s = 0.f;
#pragma unroll
      for (int j1 = 0; j1 < 16; ++j1) s += r[j1] * q1s[i1 * 16 + j1];
      orow[i1 * 256 + i2 * 16 + i3] = f2bf(s);
    }
  }
}

// ---------- transpose 4096x4096 bf16 ----------
__global__ __launch_bounds__(256) void k_transpose(const unsigned short* __restrict__ in,
                                                   unsigned short* __restrict__ out) {
  __shared__ unsigned short tile[64][68];
  int bx = blockIdx.x & 63;
  int by = blockIdx.x >> 6;
  int t = threadIdx.x;
#pragma unroll
  for (int q = 0; q < 4; ++q) {
    int i = t + q * 256;
    int r = i >> 4;
    int c = (i & 15) * 4;
    v4u16 v = *(const v4u16*)(in + (size_t)(by * 64 + r) * 4096 + bx * 64 + c);
    tile[r][c] = v[0]; tile[r][c + 1] = v[1]; tile[r][c + 2] = v[2]; tile[r][c + 3] = v[3];
  }
  __syncthreads();
#pragma unroll
  for (int q = 0; q < 4; ++q) {
    int i = t + q * 256;
    int r = i >> 4;
    int c = (i & 15) * 4;
    v4u16 v;
    v[0] = tile[c][r]; v[1] = tile[c + 1][r]; v[2] = tile[c + 2][r]; v[3] = tile[c + 3][r];
    *(v4u16*)(out + (size_t)(bx * 64 + r) * 4096 + by * 64 + c) = v;
  }
}

// ---------- 256x256 NT GEMM, m201-faithful (R14 best) ----------
// BM=BN=256, BK=64, 512 thr (2Mx4N waves), wave tile 128x64.
// LDS shorts [65536] = [dbuf 2][mat 2][half 2][row 128][64]: off = d*32768 +
// mat*16384 + half*8192 + row*64 + chunk'*8, chunk' = chunk ^ (row&7).
// Tile t (buf d=t&1) = 4 quadrant phases (16 MFMA each, K64 chained);
// stage halves per the verified ledger; vmcnt(4) at tile end.

#define STGH(MATP, MI, H, D, T) do {                                       \
    gl_lds16((MATP) + (size_t)((H) * 128) * K + (T) * 64,                  \
             &lds[(D) * 32768 + (MI) * 16384 + (H) * 8192 + tid * 8]);     \
    gl_lds16((MATP) + (size_t)((H) * 128 + 64) * K + (T) * 64,             \
             &lds[(D) * 32768 + (MI) * 16384 + (H) * 8192 + 4096 + tid * 8]); \
  } while (0)

#define RA(D, I, S) \
  (*(const v8s*)&lds[(D) * 32768 + abase + (I) * 1024 + ((S) ? kc1 : kc0)])
#define RB(D, J, S) \
  (*(const v8s*)&lds[(D) * 32768 + 16384 + bbase + (J) * 1024 + ((S) ? kc1 : kc0)])

#define MM(I, NN, AV, BV) \
  acc[(I)][(NN)] = __builtin_amdgcn_mfma_f32_16x16x32_bf16(AV, BV, acc[(I)][(NN)], 0, 0, 0)

#define MMQ(IQ, JQ, BX) do {                                               \
    MM((IQ)+0, (JQ)+0, aF[0][0], BX[0][0]); MM((IQ)+1, (JQ)+0, aF[1][0], BX[0][0]); \
    MM((IQ)+2, (JQ)+0, aF[2][0], BX[0][0]); MM((IQ)+3, (JQ)+0, aF[3][0], BX[0][0]); \
    MM((IQ)+0, (JQ)+1, aF[0][0], BX[1][0]); MM((IQ)+1, (JQ)+1, aF[1][0], BX[1][0]); \
    MM((IQ)+2, (JQ)+1, aF[2][0], BX[1][0]); MM((IQ)+3, (JQ)+1, aF[3][0], BX[1][0]); \
    MM((IQ)+0, (JQ)+0, aF[0][1], BX[0][1]); MM((IQ)+1, (JQ)+0, aF[1][1], BX[0][1]); \
    MM((IQ)+2, (JQ)+0, aF[2][1], BX[0][1]); MM((IQ)+3, (JQ)+0, aF[3][1], BX[0][1]); \
    MM((IQ)+0, (JQ)+1, aF[0][1], BX[1][1]); MM((IQ)+1, (JQ)+1, aF[1][1], BX[1][1]); \
    MM((IQ)+2, (JQ)+1, aF[2][1], BX[1][1]); MM((IQ)+3, (JQ)+1, aF[3][1], BX[1][1]); \
  } while (0)

#define PH(RD, STGX, HINT8, IQ, JQ, BX, DOVM) do {                         \
    RD;                                                                    \
    STGX;                                                                  \
    if (HINT8) asm volatile("s_waitcnt lgkmcnt(8)" ::: "memory");          \
    __builtin_amdgcn_sched_barrier(0);                                     \
    __builtin_amdgcn_s_barrier();                                          \
    asm volatile("s_waitcnt lgkmcnt(0)" ::: "memory");                     \
    __builtin_amdgcn_sched_barrier(0);                                     \
    __builtin_amdgcn_s_setprio(1);                                         \
    MMQ(IQ, JQ, BX);                                                       \
    __builtin_amdgcn_s_setprio(0);                                         \
    if (DOVM) asm volatile("s_waitcnt vmcnt(4)" ::: "memory");             \
    __builtin_amdgcn_s_barrier();                                          \
    __builtin_amdgcn_sched_barrier(0);                                     \
  } while (0)

#define RD_Q0(D) do {                                                      \
    aF[0][0]=RA(D,0,0); aF[0][1]=RA(D,0,1); aF[1][0]=RA(D,1,0); aF[1][1]=RA(D,1,1); \
    aF[2][0]=RA(D,2,0); aF[2][1]=RA(D,2,1); aF[3][0]=RA(D,3,0); aF[3][1]=RA(D,3,1); \
    bF0[0][0]=RB(D,0,0); bF0[0][1]=RB(D,0,1); bF0[1][0]=RB(D,1,0); bF0[1][1]=RB(D,1,1); \
  } while (0)
#define RD_Q1(D) do {                                                      \
    bF1[0][0]=RB(D,2,0); bF1[0][1]=RB(D,2,1); bF1[1][0]=RB(D,3,0); bF1[1][1]=RB(D,3,1); \
  } while (0)
#define RD_Q2(D) do {                                                      \
    aF[0][0]=RA(D,4,0); aF[0][1]=RA(D,4,1); aF[1][0]=RA(D,5,0); aF[1][1]=RA(D,5,1); \
    aF[2][0]=RA(D,6,0); aF[2][1]=RA(D,6,1); aF[3][0]=RA(D,7,0); aF[3][1]=RA(D,7,1); \
  } while (0)

template <int OUT_BF16>
__global__ __launch_bounds__(512, 2) void k_gemm256(const unsigned short* __restrict__ A,
                                                    const unsigned short* __restrict__ B,
                                                    void* __restrict__ Cv,
                                                    int K, int N, int nbn) {
  __shared__ unsigned short lds[65536];  // 128 KiB
  const int NT = K >> 6;                 // 64
  const int NM = NT - 1;
  int nwg = gridDim.x;
  int bid = blockIdx.x;
  int wg = (bid & 7) * (nwg >> 3) + (bid >> 3);  // bijective XCD swizzle (nwg%8==0)
  int bm = wg / nbn, bn = wg % nbn;
  int tid = threadIdx.x;
  int lane = tid & 63;
  int l4 = lane & 15;
  int wid = tid >> 6;
  int wr = wid >> 2, wc = wid & 3;

  // staging source (pre-swizzled 8-chunk XOR): thread -> row srow, chunk tid&7
  int srow = tid >> 3;                                   // 0..63
  int scol = ((tid & 7) ^ (srow & 7)) * 8;               // shorts
  const unsigned short* Ap = A + (size_t)(bm * 256 + srow) * K + scol;
  const unsigned short* Bp = B + (size_t)(bn * 256 + srow) * K + scol;

  // frag-read lane constants (shorts): chunk' = ((lane>>4)+4s) ^ (l4&7)
  int kc0 = (((lane >> 4)) ^ (l4 & 7)) * 8;
  int kc1 = (((lane >> 4) + 4) ^ (l4 & 7)) * 8;
  int abase = wr * 8192 + l4 * 64;                       // A: half = wr
  int bbase = (wc >> 1) * 8192 + ((wc & 1) * 64 + l4) * 64;  // B: half = wc>>1

  v4f acc[8][4];
#pragma unroll
  for (int i = 0; i < 8; ++i)
#pragma unroll
    for (int j = 0; j < 4; ++j) acc[i][j] = (v4f){0.f, 0.f, 0.f, 0.f};
  v8s aF[4][2];
  v8s bF0[2][2];
  v8s bF1[2][2];

  // prologue: t0 {Ah0,Ah1,Bh0,Bh1} -> buf0; t1 {Bh0,Bh1} -> buf1 (12 loads)
  STGH(Ap, 0, 0, 0, 0); STGH(Ap, 0, 1, 0, 0);
  STGH(Bp, 1, 0, 0, 0); STGH(Bp, 1, 1, 0, 0);
  STGH(Bp, 1, 0, 1, 1); STGH(Bp, 1, 1, 1, 1);
  asm volatile("s_waitcnt vmcnt(4)" ::: "memory");
  __builtin_amdgcn_s_barrier();
  __builtin_amdgcn_sched_barrier(0);

  for (int it = 0; it < NT / 2; ++it) {
    int sA0 = (2 * it + 1) & NM;  // A-target for tile t0 = t0+1 (buf1)
    int sB0 = (2 * it + 2) & NM;  // B-target for tile t0 = t0+2 (buf0)
    int sB1 = (2 * it + 3) & NM;  // B-target for tile t1 = t1+2 (buf1)
    // tile t0 (buf 0)
    PH(RD_Q0(0), STGH(Ap, 0, 0, 1, sA0), 1, 0, 0, bF0, 0);
    PH(RD_Q1(0), STGH(Ap, 0, 1, 1, sA0), 0, 0, 2, bF1, 0);
    PH(RD_Q2(0), STGH(Bp, 1, 0, 0, sB0), 0, 4, 0, bF0, 0);
    PH(,         STGH(Bp, 1, 1, 0, sB0), 0, 4, 2, bF1, 1);
    // tile t1 (buf 1)
    PH(RD_Q0(1), STGH(Ap, 0, 0, 0, sB0), 1, 0, 0, bF0, 0);
    PH(RD_Q1(1), STGH(Ap, 0, 1, 0, sB0), 0, 0, 2, bF1, 0);
    PH(RD_Q2(1), STGH(Bp, 1, 0, 1, sB1), 0, 4, 0, bF0, 0);
    PH(,         STGH(Bp, 1, 1, 1, sB1), 0, 4, 2, bF1, 1);
  }
  asm volatile("s_waitcnt vmcnt(0)" ::: "memory");

  int row0 = bm * 256 + wr * 128 + ((lane >> 4) << 2);
  int col0 = bn * 256 + wc * 64 + l4;
  if (OUT_BF16) {
    unsigned short* Cp = (unsigned short*)Cv;
#pragma unroll
    for (int m = 0; m < 8; ++m)
#pragma unroll
      for (int n = 0; n < 4; ++n)
#pragma unroll
        for (int r = 0; r < 4; ++r)
          Cp[(size_t)(row0 + m * 16 + r) * N + col0 + n * 16] = f2bf(acc[m][n][r]);
  } else {
    float* Cp = (float*)Cv;
#pragma unroll
    for (int m = 0; m < 8; ++m)
#pragma unroll
      for (int n = 0; n < 4; ++n)
#pragma unroll
        for (int r = 0; r < 4; ++r)
          Cp[(size_t)(row0 + m * 16 + r) * N + col0 + n * 16] = acc[m][n][r];
  }
}

extern "C" void kernel_launch(void* const* d_in, const int* in_sizes, int n_in,
                              void* d_out, int out_size, void* d_ws, size_t ws_size,
                              hipStream_t stream) {
  const float* x = (const float*)d_in[0];
  const float* U = (const float*)d_in[1];
  const float* S = (const float*)d_in[2];
  const float* V = (const float*)d_in[3];
  const float* delta = (const float*)d_in[4];
  const float* Q1 = (const float*)d_in[5];
  const float* Q2 = (const float*)d_in[6];
  const float* Q3 = (const float*)d_in[7];

  char* ws = (char*)d_ws;
  unsigned short* Us = (unsigned short*)(ws);
  unsigned short* Mt = (unsigned short*)(ws + 33554432);
  unsigned short* xb = (unsigned short*)(ws + 67108864);
  char* oc = (char*)d_out;
  unsigned short* Vo = (unsigned short*)(oc);
  unsigned short* VoT = (unsigned short*)(oc + 33554432);
  float* out = (float*)d_out;

  k_prep_us<<<8192, 256, 0, stream>>>(U, S, delta, Us);
  k_kron<<<4096, 256, 0, stream>>>(V, Q1, Q2, Q3, Vo);
  k_transpose<<<4096, 256, 0, stream>>>(Vo, VoT);
  k_prep_x<<<16384, 256, 0, stream>>>(x, xb);
  // Mt[o,i] = sum_k Us[o,k] * VoT[i,k]   (4096x4096x4096)
  k_gemm256<1><<<256, 512, 0, stream>>>(Us, VoT, (void*)Mt, 4096, 4096, 16);
  // out[n,o] = sum_i xb[n,i] * Mt[o,i]   (8192x4096x4096)
  k_gemm256<0><<<512, 512, 0, stream>>>(xb, Mt, (void*)out, 4096, 4096, 16);
}